// Round 5
// baseline (541.347 us; speedup 1.0000x reference)
//
#include <hip/hip_runtime.h>
#include <stdint.h>

#define NB 64    // scan steps (B)
#define NT 128   // T
#define NF 1024  // F
#define NS 512   // S
#define NM 2048  // M
#define MAXNEW 128   // max new pool vectors: <=2 per step * 64 steps
#define NSLOT 16     // LDS row-cache slots (4KB each)
#define SQRT_S 22.627417f  // correctly-rounded f32 of sqrt(512)

// 0.5 - hard_sigmoid(x - s), numpy-identical per-op rounding.
__device__ __forceinline__ float comp_of(float x, float s) {
    float d = __fsub_rn(x, s);
    float t = __fadd_rn(__fmul_rn(0.2f, d), 0.5f);
    t = fminf(fmaxf(t, 0.0f), 1.0f);
    return __fsub_rn(0.5f, t);
}

// order-isomorphic f32 <-> u32 (NaN-free). Invertible: decode is bit-exact.
__device__ __forceinline__ unsigned fkey(float x) {
    unsigned u = __float_as_uint(x);
    return (u & 0x80000000u) ? ~u : (u | 0x80000000u);
}
__device__ __forceinline__ float fkeyInv(unsigned k) {
    return (k & 0x80000000u) ? __uint_as_float(k & 0x7fffffffu) : __uint_as_float(~k);
}
// larger key = larger value, ties -> smaller m (np.argmax first-index semantics)
__device__ __forceinline__ unsigned long long packKey(float v, int m) {
    return ((unsigned long long)fkey(v) << 32) | (unsigned)(NM - m);
}

// ---- stage 1: per (b, 64-route segment): column min/max, float4-vectorized ----
__global__ void k_routes1(const float* __restrict__ mr,
                          float* __restrict__ pMin, float* __restrict__ pMax) {
    int b = blockIdx.x, seg = blockIdx.y, t = threadIdx.x;
    const float* base = mr + ((size_t)b * NS + (size_t)seg * (NS / 8)) * NF + 4 * t;
    float4 mn = *(const float4*)base, mx = mn;
    #pragma unroll 4
    for (int s = 1; s < NS / 8; ++s) {
        float4 v = *(const float4*)(base + (size_t)s * NF);
        mn.x = fminf(mn.x, v.x); mx.x = fmaxf(mx.x, v.x);
        mn.y = fminf(mn.y, v.y); mx.y = fmaxf(mx.y, v.y);
        mn.z = fminf(mn.z, v.z); mx.z = fmaxf(mx.z, v.z);
        mn.w = fminf(mn.w, v.w); mx.w = fmaxf(mx.w, v.w);
    }
    size_t o = ((size_t)seg * NB + b) * NF + 4 * t;
    *(float4*)(pMin + o) = mn;
    *(float4*)(pMax + o) = mx;
}

// ---- stage 2: combine 8 segments + epilogue (UMS, cond_s partials, upd_idx_s) ----
// comp is monotone non-increasing in mr (per-op rounding is monotone), so column
// extremes give max|comp_sp| exactly; cs >= 0 makes max_s attained at column max.
__global__ void k_routes2(const float* __restrict__ pMin, const float* __restrict__ pMax,
                          const float* __restrict__ mr, const float* __restrict__ states,
                          float* __restrict__ UMS, float* __restrict__ updIdxS,
                          int* __restrict__ condSpart) {
    int b = blockIdx.x, t = threadIdx.x;
    float4 mn = make_float4(INFINITY, INFINITY, INFINITY, INFINITY);
    float4 mx = make_float4(-INFINITY, -INFINITY, -INFINITY, -INFINITY);
    #pragma unroll
    for (int seg = 0; seg < 8; ++seg) {
        size_t o = ((size_t)seg * NB + b) * NF + 4 * t;
        float4 a = *(const float4*)(pMin + o);
        float4 c = *(const float4*)(pMax + o);
        mn.x = fminf(mn.x, a.x); mx.x = fmaxf(mx.x, c.x);
        mn.y = fminf(mn.y, a.y); mx.y = fmaxf(mx.y, c.y);
        mn.z = fminf(mn.z, a.z); mx.z = fmaxf(mx.z, c.z);
        mn.w = fminf(mn.w, a.w); mx.w = fmaxf(mx.w, c.w);
    }
    float4 sv = *(const float4*)(states + ((size_t)b * NT + NT - 1) * NF + 4 * t);
    float4 hi, lo4, cs, om, ums;
    hi.x = comp_of(mn.x, sv.x); lo4.x = comp_of(mx.x, sv.x);
    hi.y = comp_of(mn.y, sv.y); lo4.y = comp_of(mx.y, sv.y);
    hi.z = comp_of(mn.z, sv.z); lo4.z = comp_of(mx.z, sv.z);
    hi.w = comp_of(mn.w, sv.w); lo4.w = comp_of(mx.w, sv.w);
    cs.x = __fmul_rn(SQRT_S, fmaxf(hi.x, -lo4.x)); om.x = __fsub_rn(1.0f, cs.x);
    cs.y = __fmul_rn(SQRT_S, fmaxf(hi.y, -lo4.y)); om.y = __fsub_rn(1.0f, cs.y);
    cs.z = __fmul_rn(SQRT_S, fmaxf(hi.z, -lo4.z)); om.z = __fsub_rn(1.0f, cs.z);
    cs.w = __fmul_rn(SQRT_S, fmaxf(hi.w, -lo4.w)); om.w = __fsub_rn(1.0f, cs.w);
    ums.x = __fadd_rn(__fmul_rn(mx.x, cs.x), __fmul_rn(sv.x, om.x));
    ums.y = __fadd_rn(__fmul_rn(mx.y, cs.y), __fmul_rn(sv.y, om.y));
    ums.z = __fadd_rn(__fmul_rn(mx.z, cs.z), __fmul_rn(sv.z, om.z));
    ums.w = __fadd_rn(__fmul_rn(mx.w, cs.w), __fmul_rn(sv.w, om.w));
    *(float4*)(UMS + (size_t)b * NF + 4 * t) = ums;

    __shared__ int anyf;
    if (t == 0) anyf = 0;
    __syncthreads();
    if (hi.x >= 0.45f || hi.y >= 0.45f || hi.z >= 0.45f || hi.w >= 0.45f) atomicOr(&anyf, 1);
    __syncthreads();
    if (t == 0) {
        condSpart[4 * b + 0] = anyf;
        condSpart[4 * b + 1] = 0;
        condSpart[4 * b + 2] = 0;
        condSpart[4 * b + 3] = 0;
    }
    if (t == 255) {
        float mr0l = mr[(size_t)b * NS * NF + NF - 1];  // mr[b, 0, F-1]
        updIdxS[b] = __fadd_rn(__fmul_rn(mr0l, cs.w), __fmul_rn(sv.w, om.w));
    }
}

// ---- fallback single-stage (small ws), scalar, writes per-quarter partials ----
__global__ void k_routes(const float* __restrict__ mr, const float* __restrict__ states,
                         float* __restrict__ UMS, float* __restrict__ updIdxS,
                         int* __restrict__ condSpart) {
    int b = blockIdx.x;
    int f = blockIdx.y * blockDim.x + threadIdx.x;
    const float* base = mr + (size_t)b * NS * NF + f;
    float mn0 = base[0],      mx0 = mn0;
    float mn1 = base[NF],     mx1 = mn1;
    float mn2 = base[2 * NF], mx2 = mn2;
    float mn3 = base[3 * NF], mx3 = mn3;
    #pragma unroll 4
    for (int s = 4; s < NS; s += 4) {
        float v0 = base[(size_t)s * NF];
        float v1 = base[(size_t)(s + 1) * NF];
        float v2 = base[(size_t)(s + 2) * NF];
        float v3 = base[(size_t)(s + 3) * NF];
        mn0 = fminf(mn0, v0); mx0 = fmaxf(mx0, v0);
        mn1 = fminf(mn1, v1); mx1 = fmaxf(mx1, v1);
        mn2 = fminf(mn2, v2); mx2 = fmaxf(mx2, v2);
        mn3 = fminf(mn3, v3); mx3 = fmaxf(mx3, v3);
    }
    float mn = fminf(fminf(mn0, mn1), fminf(mn2, mn3));
    float mx = fmaxf(fmaxf(mx0, mx1), fmaxf(mx2, mx3));
    float sv = states[((size_t)b * NT + NT - 1) * NF + f];
    float compHi = comp_of(mn, sv);
    float compLo = comp_of(mx, sv);
    float maxabs = fmaxf(compHi, -compLo);
    float cs   = __fmul_rn(SQRT_S, maxabs);
    float omcs = __fsub_rn(1.0f, cs);
    UMS[b * NF + f] = __fadd_rn(__fmul_rn(mx, cs), __fmul_rn(sv, omcs));

    __shared__ int anyf;
    if (threadIdx.x == 0) anyf = 0;
    __syncthreads();
    if (compHi >= 0.45f) atomicOr(&anyf, 1);
    __syncthreads();
    if (threadIdx.x == 0) condSpart[4 * b + blockIdx.y] = anyf;

    if (f == NF - 1) {
        float mr0l = mr[(size_t)b * NS * NF + NF - 1];
        updIdxS[b] = __fadd_rn(__fmul_rn(mr0l, cs), __fmul_rn(sv, omcs));
    }
}

// Per original memory row m: bit b = any_f(comp(mem[m,f], s_b[f]) >= 0.45)
__global__ void k_predorig(const float* __restrict__ memory, const float* __restrict__ states,
                           unsigned long long* __restrict__ predOrig) {
    int m = blockIdx.x, t = threadIdx.x;
    const float4* rowp = (const float4*)(memory + (size_t)m * NF);
    float4 v = rowp[t];
    unsigned long long mask = 0ull;
    for (int b = 0; b < NB; ++b) {
        const float4* sp = (const float4*)(states + ((size_t)b * NT + NT - 1) * NF);
        float4 s = sp[t];
        bool p = (comp_of(v.x, s.x) >= 0.45f) | (comp_of(v.y, s.y) >= 0.45f)
               | (comp_of(v.z, s.z) >= 0.45f) | (comp_of(v.w, s.w) >= 0.45f);
        if (p) mask |= (1ull << b);
    }
    __shared__ unsigned long long sm[256];
    sm[t] = mask;
    __syncthreads();
    for (int off = 128; off > 0; off >>= 1) {
        if (t < off) sm[t] |= sm[t + off];
        __syncthreads();
    }
    if (t == 0) predOrig[m] = sm[0];
}

// Deferred output materialization: rows are immutable once created.
__global__ void k_out(const unsigned long long* __restrict__ srcRec, float* __restrict__ out) {
    int b = blockIdx.x, t = threadIdx.x;
    const float* src = (const float*)(uintptr_t)srcRec[b];
    *(float4*)(out + (size_t)b * NF + 4 * t) = *(const float4*)(src + 4 * t);
}

// Sequential scan, single block. Carry compressed: rowid[m] -> pool vector.
// Pool vectors LDS-cached (write-through to vecq); outputs deferred to k_out.
__global__ void __launch_bounds__(256) k_scan(
    const float* __restrict__ states, const float* __restrict__ memory,
    const float* __restrict__ indexIn, const float* __restrict__ UMS,
    const float* __restrict__ updIdxS, const int* __restrict__ condSpart,
    const unsigned long long* __restrict__ predOrig, float* __restrict__ vecq,
    unsigned long long* __restrict__ srcRec, float* __restrict__ out)
{
    __shared__ float cacheRow[NSLOT][NF];          // 64 KB row cache
    __shared__ uint16_t rowid[NM];
    __shared__ float idxv[NM];
    __shared__ float cqArr[NM];
    __shared__ float curLast[NM];                  // last element of row m's vector
    __shared__ unsigned long long pOrig[NM];
    __shared__ const float* poolPtr[MAXNEW];       // global ptr of each pool vector
    __shared__ unsigned char liveStamp[MAXNEW];    // == b+1 iff live at step b
    __shared__ short poolSlot[MAXNEW];             // cache slot or -1
    __shared__ uint16_t slotPool[NSLOT];           // reverse map (0xFFFF free)
    __shared__ unsigned long long redA[4], redB[4], redC[4];
    __shared__ int flagQArr[NB];
    __shared__ int chosen1, chosen2, liveLoSh;

    int t = threadIdx.x;
    int lane = t & 63, wid = t >> 6;

    for (int m = t; m < NM; m += 256) {
        rowid[m] = (uint16_t)m;
        idxv[m] = indexIn[m];
        curLast[m] = memory[(size_t)m * NF + NF - 1];
        pOrig[m] = predOrig[m];
    }
    for (int i = t; i < MAXNEW; i += 256) { liveStamp[i] = 0; poolSlot[i] = -1; }
    for (int i = t; i < NB; i += 256) flagQArr[i] = 0;
    if (t < NSLOT) slotPool[t] = 0xFFFF;
    if (t == 0) liveLoSh = 0;
    int nCnt = 0;  // uniform

    // prefetch step-0 inputs
    float4 s4c = *(const float4*)(states + ((size_t)(NT - 1)) * NF + 4 * t);
    float4 u4c = *(const float4*)(UMS + 4 * t);
    int4   cSc = *(const int4*)(condSpart);
    float uIdxSc = updIdxS[0];
    float sLc = states[((size_t)(NT - 1)) * NF + NF - 1];
    float uLc = UMS[NF - 1];

    for (int b = 0; b < NB; ++b) {
        // issue next-step prefetch (consumed at loop end)
        int bn = (b + 1 < NB) ? b + 1 : b;
        const float* sGn = states + ((size_t)bn * NT + NT - 1) * NF;
        float4 s4n = *(const float4*)(sGn + 4 * t);
        float4 u4n = *(const float4*)(UMS + (size_t)bn * NF + 4 * t);
        int4   cSn = *(const int4*)(condSpart + 4 * bn);
        float uIdxSn = updIdxS[bn];
        float sLn = sGn[NF - 1];
        float uLn = UMS[(size_t)bn * NF + NF - 1];

        const float* sG = states + ((size_t)b * NT + NT - 1) * NF;
        float sF = sLc, r = sLc;
        unsigned char stamp = (unsigned char)(b + 1);

        // ---- phase 1: cq per row, max + first-argmax; live marking; orig bits ----
        unsigned long long lk1 = 0; bool lp = false;
        #pragma unroll
        for (int k = 0; k < NM / 256; ++k) {
            int m = t + 256 * k;
            float c = comp_of(curLast[m], sF);
            cqArr[m] = c;
            int p = rowid[m];
            if (p < NM) { if ((pOrig[p] >> b) & 1ull) lp = true; }
            else liveStamp[p - NM] = stamp;
            unsigned long long kk = packKey(c, m);
            if (kk > lk1) lk1 = kk;
        }
        #pragma unroll
        for (int off = 32; off > 0; off >>= 1) {
            unsigned long long o = __shfl_down(lk1, off, 64);
            if (o > lk1) lk1 = o;
        }
        if (lane == 0) redA[wid] = lk1;
        if (lp) atomicOr(&flagQArr[b], 1);
        __syncthreads();   // B1
        unsigned long long bk1 = redA[0];
        #pragma unroll
        for (int w = 1; w < 4; ++w) if (redA[w] > bk1) bk1 = redA[w];
        int   mi    = NM - (int)(bk1 & 0xffffffffull);
        float cqmax = fkeyInv((unsigned)(bk1 >> 32));   // bit-exact cqArr[mi]
        bool condQorig = (flagQArr[b] != 0);

        // ---- phase 2: pool-vector part of cond_q; slot pre-selection (t0) ----
        int lo = liveLoSh;                         // dead-forever => monotone-safe read
        while (lo < nCnt && liveStamp[lo] != stamp) ++lo;
        if (!condQorig) {
            bool pp = false;
            for (int i = lo; i < nCnt; ++i) {      // uniform loop, few live entries
                if (liveStamp[i] == stamp) {
                    int sl = poolSlot[i];
                    const float* vp = (sl >= 0) ? &cacheRow[sl][0] : poolPtr[i];
                    float4 v = *(const float4*)(vp + 4 * t);
                    if (comp_of(v.x, s4c.x) >= 0.45f || comp_of(v.y, s4c.y) >= 0.45f ||
                        comp_of(v.z, s4c.z) >= 0.45f || comp_of(v.w, s4c.w) >= 0.45f) pp = true;
                }
            }
            if (pp) atomicOr(&flagQArr[b], 1);
        }
        if (t == 0) {
            liveLoSh = lo;
            int c1 = -1, c2 = -1;
            for (int s2 = 0; s2 < NSLOT; ++s2) {
                int id = slotPool[s2];
                bool fr = (id == 0xFFFF) || (liveStamp[id] != stamp);
                if (fr) { if (c1 < 0) c1 = s2; else { c2 = s2; break; } }
            }
            chosen1 = c1; chosen2 = c2;
        }
        __syncthreads();   // B2
        bool cond_q = (flagQArr[b] != 0);

        // ---- phase 3: q-update ----
        if (cond_q) {
            int nid = nCnt;
            int pmi = rowid[mi];
            float idxmi   = idxv[mi];       // mi is a max row: never written below
            float srcLast = curLast[mi];
            float c = cqmax, omc = __fsub_rn(1.0f, c);
            float updIdxQ = __fadd_rn(__fmul_rn(idxmi, omc), __fmul_rn(r, c));
            float oLast   = __fadd_rn(__fmul_rn(srcLast, omc), __fmul_rn(sF, c));
            float4 v;
            if (pmi < NM) {
                v = *(const float4*)(memory + (size_t)pmi * NF + 4 * t);
            } else {
                int sl = poolSlot[pmi - NM];
                const float* sp = (sl >= 0) ? &cacheRow[sl][0] : poolPtr[pmi - NM];
                v = *(const float4*)(sp + 4 * t);
            }
            float4 o;
            o.x = __fadd_rn(__fmul_rn(v.x, omc), __fmul_rn(s4c.x, c));
            o.y = __fadd_rn(__fmul_rn(v.y, omc), __fmul_rn(s4c.y, c));
            o.z = __fadd_rn(__fmul_rn(v.z, omc), __fmul_rn(s4c.z, c));
            o.w = __fadd_rn(__fmul_rn(v.w, omc), __fmul_rn(s4c.w, c));
            *(float4*)(vecq + (size_t)b * NF + 4 * t) = o;        // write-through
            int sl1 = chosen1;
            if (sl1 >= 0) *(float4*)(&cacheRow[sl1][4 * t]) = o;
            if (t == 0) {
                poolPtr[nid] = vecq + (size_t)b * NF;
                liveStamp[nid] = stamp;
                if (sl1 >= 0) {
                    int old = slotPool[sl1];
                    if (old != 0xFFFF) poolSlot[old] = -1;
                    slotPool[sl1] = (uint16_t)nid;
                    poolSlot[nid] = (short)sl1;
                } else poolSlot[nid] = -1;
            }
            int nidTag = NM + nid;
            #pragma unroll
            for (int k = 0; k < NM / 256; ++k) {
                int m = t + 256 * k;
                if (!(cqArr[m] == cqmax)) {
                    rowid[m] = (uint16_t)nidTag;
                    idxv[m] = updIdxQ;
                    curLast[m] = oLast;
                }
            }
            nCnt++;
        }
        __syncthreads();   // B3

        // ---- phase 4/5 merged: s-update or empty-update (mutually exclusive) ----
        bool cond_s = ((cSc.x | cSc.y | cSc.z | cSc.w) != 0);
        bool cond_e = (!cond_q) && (!cond_s);
        if (cond_s || cond_e) {
            int sid = nCnt;
            unsigned long long lk2 = 0;
            #pragma unroll
            for (int k = 0; k < NM / 256; ++k) {
                int m = t + 256 * k;
                unsigned long long kk = packKey(-idxv[m], m);
                if (kk > lk2) lk2 = kk;
            }
            #pragma unroll
            for (int off = 32; off > 0; off >>= 1) {
                unsigned long long o = __shfl_down(lk2, off, 64);
                if (o > lk2) lk2 = o;
            }
            if (lane == 0) redB[wid] = lk2;
            __syncthreads();   // B4
            unsigned long long bk2 = redB[0];
            #pragma unroll
            for (int w = 1; w < 4; ++w) if (redB[w] > bk2) bk2 = redB[w];
            float mxneg = fkeyInv((unsigned)(bk2 >> 32));   // bit-exact max(-idx)
            float newIdx  = cond_s ? uIdxSc : r;
            float newLast = cond_s ? uLc : sF;
            float4 w4 = cond_s ? u4c : s4c;
            int sl2 = chosen2;
            if (sl2 >= 0) *(float4*)(&cacheRow[sl2][4 * t]) = w4;
            if (t == 0) {
                poolPtr[sid] = cond_s ? (UMS + (size_t)b * NF) : sG;
                liveStamp[sid] = stamp;
                if (sl2 >= 0) {
                    int old = slotPool[sl2];
                    if (old != 0xFFFF) poolSlot[old] = -1;
                    slotPool[sl2] = (uint16_t)sid;
                    poolSlot[sid] = (short)sl2;
                } else poolSlot[sid] = -1;
            }
            int sidTag = NM + sid;
            #pragma unroll
            for (int k = 0; k < NM / 256; ++k) {
                int m = t + 256 * k;
                if (idxv[m] == mxneg) {
                    rowid[m] = (uint16_t)sidTag;
                    idxv[m] = newIdx;
                    curLast[m] = newLast;
                }
            }
            nCnt++;
        }
        __syncthreads();   // B5

        // ---- phase 6: leader = first-argmax(idx); record ptr only ----
        unsigned long long lk3 = 0;
        #pragma unroll
        for (int k = 0; k < NM / 256; ++k) {
            int m = t + 256 * k;
            unsigned long long kk = packKey(idxv[m], m);
            if (kk > lk3) lk3 = kk;
        }
        #pragma unroll
        for (int off = 32; off > 0; off >>= 1) {
            unsigned long long o = __shfl_down(lk3, off, 64);
            if (o > lk3) lk3 = o;
        }
        if (lane == 0) redC[wid] = lk3;
        __syncthreads();   // B6
        if (t == 0) {
            unsigned long long bk3 = redC[0];
            #pragma unroll
            for (int w = 1; w < 4; ++w) if (redC[w] > bk3) bk3 = redC[w];
            int   li   = NM - (int)(bk3 & 0xffffffffull);
            float lidx = fkeyInv((unsigned)(bk3 >> 32));
            int pl = rowid[li];
            const float* lvec = (pl < NM) ? (memory + (size_t)pl * NF) : poolPtr[pl - NM];
            srcRec[b] = (unsigned long long)(uintptr_t)lvec;
            out[(size_t)NB * NF + b] = lidx;
        }

        // rotate prefetch
        s4c = s4n; u4c = u4n; cSc = cSn; uIdxSc = uIdxSn; sLc = sLn; uLc = uLn;
    }
}

extern "C" void kernel_launch(void* const* d_in, const int* in_sizes, int n_in,
                              void* d_out, int out_size, void* d_ws, size_t ws_size,
                              hipStream_t stream) {
    (void)out_size;
    const float* states  = (const float*)d_in[0];
    const float* mr      = (const float*)d_in[1];
    const float* memory  = (const float*)d_in[2];
    const float* indexIn = (const float*)d_in[3];
    for (int i = 0; i < n_in; ++i) {
        switch (in_sizes[i]) {
            case NB * NT * NF: states  = (const float*)d_in[i]; break;
            case NB * NS * NF: mr      = (const float*)d_in[i]; break;
            case NM * NF:      memory  = (const float*)d_in[i]; break;
            case NM:           indexIn = (const float*)d_in[i]; break;
            default: break;
        }
    }
    float* out = (float*)d_out;  // f32: 64*1024 targets + 64 importances

    char* ws = (char*)d_ws;
    float* UMS      = (float*)ws;                                      // 262144
    float* updIdxS  = (float*)(ws + 262144);                           // 256
    int*   condSpart= (int*)(ws + 262400);                             // 1024
    unsigned long long* predOrig = (unsigned long long*)(ws + 263424); // 16384
    float* vecq     = (float*)(ws + 279808);                           // 262144
    unsigned long long* srcRec = (unsigned long long*)(ws + 541952);   // 512
    float* pMin     = (float*)(ws + 542464);                           // 2097152
    float* pMax     = (float*)(ws + 2639616);                          // 2097152 -> 4736768
    bool twoStage = (ws_size >= 4736768);

    if (twoStage) {
        k_routes1<<<dim3(NB, 8), 256, 0, stream>>>(mr, pMin, pMax);
        k_routes2<<<NB, 256, 0, stream>>>(pMin, pMax, mr, states, UMS, updIdxS, condSpart);
    } else {
        k_routes<<<dim3(NB, 4), 256, 0, stream>>>(mr, states, UMS, updIdxS, condSpart);
    }
    k_predorig<<<NM, 256, 0, stream>>>(memory, states, predOrig);
    k_scan<<<1, 256, 0, stream>>>(states, memory, indexIn, UMS, updIdxS, condSpart,
                                  predOrig, vecq, srcRec, out);
    k_out<<<NB, 256, 0, stream>>>(srcRec, out);
}